// Round 6
// baseline (371.761 us; speedup 1.0000x reference)
//
#include <hip/hip_runtime.h>

typedef __bf16 bf16x8 __attribute__((ext_vector_type(8)));
typedef __bf16 bf16x4 __attribute__((ext_vector_type(4)));
typedef float f32x4 __attribute__((ext_vector_type(4)));
typedef float f32x16 __attribute__((ext_vector_type(16)));
typedef unsigned short u16x8 __attribute__((ext_vector_type(8)));
typedef unsigned short u16x4 __attribute__((ext_vector_type(4)));
typedef unsigned int u32x4 __attribute__((ext_vector_type(4)));
typedef unsigned short us;

#define MM 2048
#define TT 4096

__device__ __forceinline__ us f2bf(float f){
  unsigned int u = __builtin_bit_cast(unsigned int, f);
  u = (u + 0x7fffu + ((u >> 16) & 1u)) >> 16;
  return (us)u;
}
__device__ __forceinline__ float bf2f(us u){
  unsigned int x = ((unsigned int)u) << 16;
  return __builtin_bit_cast(float, x);
}
__device__ __forceinline__ unsigned int cvt_pk_bf16(float lo, float hi){
  unsigned int r;
  asm("v_cvt_pk_bf16_f32 %0, %1, %2" : "=v"(r) : "v"(lo), "v"(hi));
  return r;
}
__device__ __forceinline__ void plane_swap(unsigned int &x, unsigned int &y){
  asm("v_permlane32_swap_b32 %0, %1" : "+v"(x), "+v"(y));
}

#define GLDS(gp, lp) __builtin_amdgcn_global_load_lds( \
    (const __attribute__((address_space(1))) unsigned int*)(gp), \
    (__attribute__((address_space(3))) unsigned int*)(lp), 16, 0, 0)

// ---------------- fp32 -> bf16 hi/lo split ----------------
__global__ __launch_bounds__(256) void split_cast(const float* __restrict__ in,
                                                  us* __restrict__ hi, us* __restrict__ lo){
  size_t i = ((size_t)blockIdx.x * 256 + threadIdx.x) * 8;
  float4 a = *(const float4*)(in + i);
  float4 b = *(const float4*)(in + i + 4);
  float v[8] = {a.x,a.y,a.z,a.w,b.x,b.y,b.z,b.w};
  u16x8 rh, rl;
  for (int j = 0; j < 8; j++){
    us h = f2bf(v[j]);
    rh[j] = h;
    rl[j] = f2bf(v[j] - bf2f(h));
  }
  *(u16x8*)(hi + i) = rh;
  *(u16x8*)(lo + i) = rl;
}

// ---------------- transpose + split: W[K][N] f32 -> Wt_hi/lo[N][K] bf16 ----------------
__global__ __launch_bounds__(256) void transpose_split(const float* __restrict__ W,
                                                       us* __restrict__ Wth, us* __restrict__ Wtl,
                                                       int K, int N){
  __shared__ float tile[32][33];
  int tx = threadIdx.x & 31, ty = threadIdx.x >> 5;   // 32 x 8
  int n0 = blockIdx.x * 32, k0 = blockIdx.y * 32;
  for (int r = 0; r < 32; r += 8)
    tile[ty + r][tx] = W[(size_t)(k0 + ty + r) * N + n0 + tx];
  __syncthreads();
  for (int r = 0; r < 32; r += 8){
    float v = tile[tx][ty + r];
    us h = f2bf(v);
    size_t idx = (size_t)(n0 + ty + r) * K + k0 + tx;
    Wth[idx] = h;
    Wtl[idx] = f2bf(v - bf2f(h));
  }
}

// ---------------- fused projection GEMM (q/k/v or k_data/v_data) ----------------
__global__ __launch_bounds__(256) void gemm_fused(const us* __restrict__ Ah, const us* __restrict__ Al,
                                                  const us* __restrict__ Bth, const us* __restrict__ Btl,
                                                  const float* __restrict__ bias,
                                                  us* __restrict__ Qh, us* __restrict__ Ql,
                                                  us* __restrict__ Kh, us* __restrict__ Kl,
                                                  us* __restrict__ VT,
                                                  int regbase, int kroff){
  __shared__ us sm[16384];  // Ah@0, Bh@4096, Al@8192, Bl@12288
  const int tid = threadIdx.x, wid = tid >> 6, lane = tid & 63;
  const int l15 = lane & 15, l16 = lane >> 4;
  const int row0 = blockIdx.y * 128, col0 = blockIdx.x * 128;
  const int region = (blockIdx.x >> 3) + regbase;
  const bool split = (region < 2);
  const int wr = (wid >> 1) * 64, wc = (wid & 1) * 64;
  f32x4 acc[4][4] = {};

  for (int k0 = 0; k0 < 1024; k0 += 32){
    for (int c = 0; c < 2; ++c){
      int i = c * 256 + tid;                           // 0..511: row=i>>2, k8=(i&3)*8
      size_t aoff = (size_t)(row0 + (i >> 2)) * 1024 + k0 + (i & 3) * 8;
      size_t boff = (size_t)(col0 + (i >> 2)) * 1024 + k0 + (i & 3) * 8;
      GLDS(Ah + aoff, &sm[c * 2048 + wid * 512]);
      GLDS(Bth + boff, &sm[4096 + c * 2048 + wid * 512]);
      if (split){
        GLDS(Al + aoff, &sm[8192 + c * 2048 + wid * 512]);
        GLDS(Btl + boff, &sm[12288 + c * 2048 + wid * 512]);
      }
    }
    __syncthreads();
    bf16x8 afh[4], bfh[4];
    for (int m = 0; m < 4; m++) afh[m] = *(const bf16x8*)&sm[(wr + m * 16 + l15) * 32 + l16 * 8];
    for (int n = 0; n < 4; n++) bfh[n] = *(const bf16x8*)&sm[4096 + (wc + n * 16 + l15) * 32 + l16 * 8];
    if (split){
      bf16x8 afl[4], bfl[4];
      for (int m = 0; m < 4; m++) afl[m] = *(const bf16x8*)&sm[8192 + (wr + m * 16 + l15) * 32 + l16 * 8];
      for (int n = 0; n < 4; n++) bfl[n] = *(const bf16x8*)&sm[12288 + (wc + n * 16 + l15) * 32 + l16 * 8];
      for (int m = 0; m < 4; m++)
        for (int n = 0; n < 4; n++){
          acc[m][n] = __builtin_amdgcn_mfma_f32_16x16x32_bf16(afh[m], bfh[n], acc[m][n], 0, 0, 0);
          acc[m][n] = __builtin_amdgcn_mfma_f32_16x16x32_bf16(afh[m], bfl[n], acc[m][n], 0, 0, 0);
          acc[m][n] = __builtin_amdgcn_mfma_f32_16x16x32_bf16(afl[m], bfh[n], acc[m][n], 0, 0, 0);
        }
    } else {
      for (int m = 0; m < 4; m++)
        for (int n = 0; n < 4; n++)
          acc[m][n] = __builtin_amdgcn_mfma_f32_16x16x32_bf16(afh[m], bfh[n], acc[m][n], 0, 0, 0);
    }
    __syncthreads();
  }

  for (int m = 0; m < 4; m++)
    for (int n = 0; n < 4; n++){
      int gcol = col0 + wc + n * 16 + l15;
      int ocol = gcol & 1023;
      float bv = bias[gcol];
      if (region == 2){                    // V -> VT[b][d][t], vectorized over 4 rows
        int r = row0 + wr + m * 16 + l16 * 4;
        u16x4 o;
        for (int j = 0; j < 4; j++) o[j] = f2bf(acc[m][n][j] + bv);
        *(u16x4*)&VT[((size_t)((r >> 11) * 1024 + ocol)) * 4096 + kroff + (r & 2047)] = o;
      } else {
        us* Ph = (region == 0) ? Qh : Kh;
        us* Pllo = (region == 0) ? Ql : Kl;
        for (int j = 0; j < 4; j++){
          int r = row0 + wr + m * 16 + l16 * 4 + j;
          size_t orow = (region == 0) ? (size_t)r
                                      : (size_t)((r >> 11) * 4096 + kroff + (r & 2047));
          float v = acc[m][n][j] + bv;
          us h = f2bf(v);
          Ph[orow * 1024 + ocol] = h;
          Pllo[orow * 1024 + ocol] = f2bf(v - bf2f(h));
        }
      }
    }
}

// ---------------- output projection GEMM (plain, fp32 out) ----------------
__global__ __launch_bounds__(256) void gemm_proj(const us* __restrict__ Ah,
                                                 const us* __restrict__ Bth,
                                                 const float* __restrict__ bias,
                                                 float* __restrict__ Co){
  __shared__ us sm[8192];
  const int tid = threadIdx.x, wid = tid >> 6, lane = tid & 63;
  const int l15 = lane & 15, l16 = lane >> 4;
  const int row0 = blockIdx.y * 128, col0 = blockIdx.x * 128;
  const int wr = (wid >> 1) * 64, wc = (wid & 1) * 64;
  f32x4 acc[4][4] = {};

  for (int k0 = 0; k0 < 1024; k0 += 32){
    for (int c = 0; c < 2; ++c){
      int i = c * 256 + tid;
      size_t aoff = (size_t)(row0 + (i >> 2)) * 1024 + k0 + (i & 3) * 8;
      size_t boff = (size_t)(col0 + (i >> 2)) * 1024 + k0 + (i & 3) * 8;
      GLDS(Ah + aoff, &sm[c * 2048 + wid * 512]);
      GLDS(Bth + boff, &sm[4096 + c * 2048 + wid * 512]);
    }
    __syncthreads();
    bf16x8 afh[4], bfh[4];
    for (int m = 0; m < 4; m++) afh[m] = *(const bf16x8*)&sm[(wr + m * 16 + l15) * 32 + l16 * 8];
    for (int n = 0; n < 4; n++) bfh[n] = *(const bf16x8*)&sm[4096 + (wc + n * 16 + l15) * 32 + l16 * 8];
    for (int m = 0; m < 4; m++)
      for (int n = 0; n < 4; n++)
        acc[m][n] = __builtin_amdgcn_mfma_f32_16x16x32_bf16(afh[m], bfh[n], acc[m][n], 0, 0, 0);
    __syncthreads();
  }

  for (int m = 0; m < 4; m++)
    for (int n = 0; n < 4; n++){
      int col = col0 + wc + n * 16 + l15;
      float bv = bias[col];
      for (int j = 0; j < 4; j++){
        int r = row0 + wr + m * 16 + l16 * 4 + j;
        Co[(size_t)r * 1024 + col] = acc[m][n][j] + bv;
      }
    }
}

// ---------------- fused attention: 32x32 MFMA, swapped operands, in-register P ----------------
// grid: B*H*(M/128); 4 waves x 32 q-rows. q = lane&31, hb = lane>>5.
// S^T C-layout (m74/m101): reg 4g+j -> t = ts*32 + 8g + 4*hb + j.
// K: LDS double-buffered (1 barrier/tile). V: direct global loads (VT rows, 16B/lane).
// P: T12 cvt_pk + v_permlane32_swap (no LDS round trip).
__global__ __launch_bounds__(256) void attn_kernel(const us* __restrict__ Qh, const us* __restrict__ Ql,
                                                   const us* __restrict__ Kh, const us* __restrict__ Kl,
                                                   const us* __restrict__ VT,
                                                   us* __restrict__ attno){
  __shared__ us Kb[2][2][64 * 72];     // [dbuf][hi/lo][64 rows][72]
  const int tid = threadIdx.x, wid = tid >> 6, lane = tid & 63;
  const int l31 = lane & 31, hb = lane >> 5, h8 = hb * 8;
  const int qt = blockIdx.x & 15;             // M/128 = 16
  const int bh = blockIdx.x >> 4;
  const int hd = (bh & 15) * 64, b = bh >> 4;
  const int qrow = qt * 128 + wid * 32 + l31;

  // Q fragments (B operand): lane holds Q[qrow][d = kk*16 + h8 + i]
  bf16x8 qfh[4], qfl[4];
  {
    const us* qp = Qh + (size_t)(b * MM + qrow) * 1024 + hd;
    const us* qq = Ql + (size_t)(b * MM + qrow) * 1024 + hd;
#pragma unroll
    for (int kk = 0; kk < 4; kk++){
      qfh[kk] = *(const bf16x8*)(qp + kk * 16 + h8);
      qfl[kk] = *(const bf16x8*)(qq + kk * 16 + h8);
    }
  }

  const int i0 = tid, i1 = 256 + tid;
  const int kt0 = i0 >> 3, kd0 = (i0 & 7) * 8;
  const int kt1 = i1 >> 3, kd1 = (i1 & 7) * 8;

#define GK(t0_, t_, d_) (((size_t)(b * TT + (t0_) + (t_))) * 1024 + hd + (d_))

  const us* vr0 = VT + ((size_t)b * 1024 + hd + l31) * 4096;
  const us* vr1 = vr0 + (size_t)32 * 4096;

  // prologue: stage K tile 0 into buf 0
  uint4 rKh0 = *(const uint4*)(Kh + GK(0, kt0, kd0));
  uint4 rKh1 = *(const uint4*)(Kh + GK(0, kt1, kd1));
  uint4 rKl0 = *(const uint4*)(Kl + GK(0, kt0, kd0));
  uint4 rKl1 = *(const uint4*)(Kl + GK(0, kt1, kd1));
  *(uint4*)&Kb[0][0][kt0 * 72 + kd0] = rKh0;
  *(uint4*)&Kb[0][0][kt1 * 72 + kd1] = rKh1;
  *(uint4*)&Kb[0][1][kt0 * 72 + kd0] = rKl0;
  *(uint4*)&Kb[0][1][kt1 * 72 + kd1] = rKl1;
  __syncthreads();

  f32x16 acc0 = {}, acc1 = {};
  float mrow = -1e30f, lrow = 0.f;
  const float cs = 0.125f * 1.44269504088896f;   // to log2 domain

  for (int t0 = 0; t0 < TT; t0 += 64){
    const int cur = (t0 >> 6) & 1;
    const bool pre = (t0 + 64 < TT);
    if (pre){
      rKh0 = *(const uint4*)(Kh + GK(t0 + 64, kt0, kd0));
      rKh1 = *(const uint4*)(Kh + GK(t0 + 64, kt1, kd1));
      rKl0 = *(const uint4*)(Kl + GK(t0 + 64, kt0, kd0));
      rKl1 = *(const uint4*)(Kl + GK(t0 + 64, kt1, kd1));
    }
    // V direct loads for THIS tile (used after softmax; latency hides under QK^T)
    uint4 v0[4], v1[4];
#pragma unroll
    for (int kk = 0; kk < 4; kk++){
      v0[kk] = *(const uint4*)(vr0 + t0 + kk * 16 + h8);
      v1[kk] = *(const uint4*)(vr1 + t0 + kk * 16 + h8);
    }

    // S^T = K . Q^T (split): frag ts holds t = ts*32 + tloc, q = l31
    const us* KbH = &Kb[cur][0][0];
    const us* KbL = &Kb[cur][1][0];
    f32x16 sfr0 = {}, sfr1 = {};
    __builtin_amdgcn_s_setprio(1);
#pragma unroll
    for (int kk = 0; kk < 4; kk++){
      bf16x8 a0h = *(const bf16x8*)&KbH[l31 * 72 + kk * 16 + h8];
      bf16x8 a0l = *(const bf16x8*)&KbL[l31 * 72 + kk * 16 + h8];
      bf16x8 a1h = *(const bf16x8*)&KbH[(32 + l31) * 72 + kk * 16 + h8];
      bf16x8 a1l = *(const bf16x8*)&KbL[(32 + l31) * 72 + kk * 16 + h8];
      sfr0 = __builtin_amdgcn_mfma_f32_32x32x16_bf16(a0h, qfh[kk], sfr0, 0, 0, 0);
      sfr0 = __builtin_amdgcn_mfma_f32_32x32x16_bf16(a0l, qfh[kk], sfr0, 0, 0, 0);
      sfr0 = __builtin_amdgcn_mfma_f32_32x32x16_bf16(a0h, qfl[kk], sfr0, 0, 0, 0);
      sfr1 = __builtin_amdgcn_mfma_f32_32x32x16_bf16(a1h, qfh[kk], sfr1, 0, 0, 0);
      sfr1 = __builtin_amdgcn_mfma_f32_32x32x16_bf16(a1l, qfh[kk], sfr1, 0, 0, 0);
      sfr1 = __builtin_amdgcn_mfma_f32_32x32x16_bf16(a1h, qfl[kk], sfr1, 0, 0, 0);
    }
    __builtin_amdgcn_s_setprio(0);

    // online softmax (log2 domain, T13 defer-max, exp2 arg via fma fold)
    float v = -1e30f;
#pragma unroll
    for (int r = 0; r < 16; r++) v = fmaxf(v, fmaxf(sfr0[r], sfr1[r]));
    float vs = v * cs;
    vs = fmaxf(vs, __shfl_xor(vs, 32, 64));
    if (!__all(vs <= mrow + 8.f)){
      float mn = fmaxf(mrow, vs);
      float rs = __builtin_amdgcn_exp2f(mrow - mn);
      mrow = mn;
      lrow *= rs;
#pragma unroll
      for (int r = 0; r < 16; r++){ acc0[r] *= rs; acc1[r] *= rs; }
    }
    const float nm = -mrow;
    float tsum = 0.f;
    unsigned int A0[4][2], A1[4][2];
#pragma unroll
    for (int g = 0; g < 4; g++){
      float e00 = __builtin_amdgcn_exp2f(__builtin_fmaf(sfr0[4*g+0], cs, nm));
      float e01 = __builtin_amdgcn_exp2f(__builtin_fmaf(sfr0[4*g+1], cs, nm));
      float e02 = __builtin_amdgcn_exp2f(__builtin_fmaf(sfr0[4*g+2], cs, nm));
      float e03 = __builtin_amdgcn_exp2f(__builtin_fmaf(sfr0[4*g+3], cs, nm));
      float e10 = __builtin_amdgcn_exp2f(__builtin_fmaf(sfr1[4*g+0], cs, nm));
      float e11 = __builtin_amdgcn_exp2f(__builtin_fmaf(sfr1[4*g+1], cs, nm));
      float e12 = __builtin_amdgcn_exp2f(__builtin_fmaf(sfr1[4*g+2], cs, nm));
      float e13 = __builtin_amdgcn_exp2f(__builtin_fmaf(sfr1[4*g+3], cs, nm));
      tsum += (e00 + e01) + (e02 + e03) + (e10 + e11) + (e12 + e13);
      A0[g][0] = cvt_pk_bf16(e00, e01);
      A0[g][1] = cvt_pk_bf16(e02, e03);
      A1[g][0] = cvt_pk_bf16(e10, e11);
      A1[g][1] = cvt_pk_bf16(e12, e13);
    }
    tsum += __shfl_xor(tsum, 32, 64);
    lrow += tsum;

    // build P fragments in-register: frag kk = {x'0, x'1, y'0, y'1},
    // (x'_i, y'_i) = permlane32_swap(A[2kkl][i], A[2kkl+1][i])
    bf16x8 pf[4];
#pragma unroll
    for (int kkl = 0; kkl < 2; kkl++){
      unsigned int x0 = A0[2*kkl][0], y0 = A0[2*kkl+1][0];
      unsigned int x1 = A0[2*kkl][1], y1 = A0[2*kkl+1][1];
      plane_swap(x0, y0);
      plane_swap(x1, y1);
      u32x4 w = {x0, x1, y0, y1};
      pf[kkl] = __builtin_bit_cast(bf16x8, w);
      unsigned int z0 = A1[2*kkl][0], t0w = A1[2*kkl+1][0];
      unsigned int z1 = A1[2*kkl][1], t1w = A1[2*kkl+1][1];
      plane_swap(z0, t0w);
      plane_swap(z1, t1w);
      u32x4 w2 = {z0, z1, t0w, t1w};
      pf[2 + kkl] = __builtin_bit_cast(bf16x8, w2);
    }

    // O^T += V^T . P^T : A = V rows (direct-loaded), B = P
    __builtin_amdgcn_s_setprio(1);
#pragma unroll
    for (int kk = 0; kk < 4; kk++){
      bf16x8 av0 = __builtin_bit_cast(bf16x8, v0[kk]);
      bf16x8 av1 = __builtin_bit_cast(bf16x8, v1[kk]);
      acc0 = __builtin_amdgcn_mfma_f32_32x32x16_bf16(av0, pf[kk], acc0, 0, 0, 0);
      acc1 = __builtin_amdgcn_mfma_f32_32x32x16_bf16(av1, pf[kk], acc1, 0, 0, 0);
    }
    __builtin_amdgcn_s_setprio(0);

    // stage next K tile into the other buffer, then single barrier
    if (pre){
      const int nxt = cur ^ 1;
      *(uint4*)&Kb[nxt][0][kt0 * 72 + kd0] = rKh0;
      *(uint4*)&Kb[nxt][0][kt1 * 72 + kd1] = rKh1;
      *(uint4*)&Kb[nxt][1][kt0 * 72 + kd0] = rKl0;
      *(uint4*)&Kb[nxt][1][kt1 * 72 + kd1] = rKl1;
    }
    __syncthreads();
  }
#undef GK

  float inv = 1.f / lrow;
  us* op = attno + (size_t)(b * MM + qrow) * 1024 + hd;
#pragma unroll
  for (int g = 0; g < 4; g++){
    bf16x4 w0, w1;
#pragma unroll
    for (int j = 0; j < 4; j++){
      w0[j] = (__bf16)(acc0[4 * g + j] * inv);
      w1[j] = (__bf16)(acc1[4 * g + j] * inv);
    }
    *(u16x4*)&op[8 * g + 4 * hb]      = __builtin_bit_cast(u16x4, w0);
    *(u16x4*)&op[32 + 8 * g + 4 * hb] = __builtin_bit_cast(u16x4, w1);
  }
}

extern "C" void kernel_launch(void* const* d_in, const int* in_sizes, int n_in,
                              void* d_out, int out_size, void* d_ws, size_t ws_size,
                              hipStream_t stream){
  const float* x      = (const float*)d_in[0];
  const float* data   = (const float*)d_in[1];
  const float* W_attn = (const float*)d_in[2];
  const float* b_attn = (const float*)d_in[3];
  const float* W_data = (const float*)d_in[4];
  const float* b_data = (const float*)d_in[5];
  const float* W_proj = (const float*)d_in[6];
  const float* b_proj = (const float*)d_in[7];
  float* out = (float*)d_out;

  char* ws = (char*)d_ws;
  us* xb_hi  = (us*)(ws + 0);            // 4096x1024 (8 MB each)
  us* xb_lo  = (us*)(ws + 8388608);
  us* db_hi  = (us*)(ws + 16777216);
  us* db_lo  = (us*)(ws + 25165824);
  us* Wat_hi = (us*)(ws + 33554432);     // 3072x1024 (6 MB each)
  us* Wat_lo = (us*)(ws + 39845888);
  us* Wdt_hi = (us*)(ws + 46137344);     // 2048x1024 (4 MB each)
  us* Wdt_lo = (us*)(ws + 50331648);
  us* Wpt_hi = (us*)(ws + 54525952);     // 1024x1024 (2 MB each)
  us* Wpt_lo = (us*)(ws + 56623104);
  us* Qh     = (us*)(ws + 58720256);     // [2][2048][1024] (8 MB each)
  us* Ql     = (us*)(ws + 67108864);
  us* Kh     = (us*)(ws + 75497472);     // [2][4096][1024] (16 MB each)
  us* Kl     = (us*)(ws + 92274688);
  us* VT     = (us*)(ws + 109051904);    // [2][1024][4096] transposed V (16 MB)
  us* attno  = (us*)(ws + 16777216);     // alias db_hi (db consumed before attn runs)

  split_cast<<<2048, 256, 0, stream>>>(x, xb_hi, xb_lo);
  split_cast<<<2048, 256, 0, stream>>>(data, db_hi, db_lo);
  transpose_split<<<dim3(96, 32), 256, 0, stream>>>(W_attn, Wat_hi, Wat_lo, 1024, 3072);
  transpose_split<<<dim3(64, 32), 256, 0, stream>>>(W_data, Wdt_hi, Wdt_lo, 1024, 2048);
  transpose_split<<<dim3(32, 32), 256, 0, stream>>>(W_proj, Wpt_hi, Wpt_lo, 1024, 1024);

  // q,k,v = x @ W_attn (+b): regions 0,1,2 -> Qh/Ql, Kh/Kl@roff0, VT@roff0
  gemm_fused<<<dim3(24, 32), 256, 0, stream>>>(xb_hi, xb_lo, Wat_hi, Wat_lo, b_attn,
                                               Qh, Ql, Kh, Kl, VT, 0, 0);
  // k_data,v_data = data @ W_data (+b): regions 1,2 -> Kh/Kl@roff2048, VT@roff2048
  gemm_fused<<<dim3(16, 32), 256, 0, stream>>>(db_hi, db_lo, Wdt_hi, Wdt_lo, b_data,
                                               nullptr, nullptr, Kh, Kl, VT, 1, 2048);

  attn_kernel<<<512, 256, 0, stream>>>(Qh, Ql, Kh, Kl, VT, attno);

  gemm_proj<<<dim3(8, 32), 256, 0, stream>>>(attno, Wpt_hi, b_proj, out);
}

// Round 7
// 354.303 us; speedup vs baseline: 1.0493x; 1.0493x over previous
//
#include <hip/hip_runtime.h>

typedef __bf16 bf16x8 __attribute__((ext_vector_type(8)));
typedef __bf16 bf16x4 __attribute__((ext_vector_type(4)));
typedef float f32x4 __attribute__((ext_vector_type(4)));
typedef float f32x16 __attribute__((ext_vector_type(16)));
typedef unsigned short u16x8 __attribute__((ext_vector_type(8)));
typedef unsigned short u16x4 __attribute__((ext_vector_type(4)));
typedef unsigned int u32x4 __attribute__((ext_vector_type(4)));
typedef unsigned short us;

#define MM 2048
#define TT 4096

__device__ __forceinline__ us f2bf(float f){
  unsigned int u = __builtin_bit_cast(unsigned int, f);
  u = (u + 0x7fffu + ((u >> 16) & 1u)) >> 16;
  return (us)u;
}
__device__ __forceinline__ float bf2f(us u){
  unsigned int x = ((unsigned int)u) << 16;
  return __builtin_bit_cast(float, x);
}
__device__ __forceinline__ unsigned int cvt_pk_bf16(float lo, float hi){
  unsigned int r;
  asm("v_cvt_pk_bf16_f32 %0, %1, %2" : "=v"(r) : "v"(lo), "v"(hi));
  return r;
}
__device__ __forceinline__ void plane_swap(unsigned int &x, unsigned int &y){
  asm("v_permlane32_swap_b32 %0, %1" : "+v"(x), "+v"(y));
}

#define GLDS(gp, lp) __builtin_amdgcn_global_load_lds( \
    (const __attribute__((address_space(1))) unsigned int*)(gp), \
    (__attribute__((address_space(3))) unsigned int*)(lp), 16, 0, 0)

// ---------------- fp32 -> bf16 hi/lo split ----------------
__global__ __launch_bounds__(256) void split_cast(const float* __restrict__ in,
                                                  us* __restrict__ hi, us* __restrict__ lo){
  size_t i = ((size_t)blockIdx.x * 256 + threadIdx.x) * 8;
  float4 a = *(const float4*)(in + i);
  float4 b = *(const float4*)(in + i + 4);
  float v[8] = {a.x,a.y,a.z,a.w,b.x,b.y,b.z,b.w};
  u16x8 rh, rl;
  for (int j = 0; j < 8; j++){
    us h = f2bf(v[j]);
    rh[j] = h;
    rl[j] = f2bf(v[j] - bf2f(h));
  }
  *(u16x8*)(hi + i) = rh;
  *(u16x8*)(lo + i) = rl;
}

// ---------------- transpose + split: W[K][N] f32 -> Wt_hi/lo[N][K] bf16 ----------------
__global__ __launch_bounds__(256) void transpose_split(const float* __restrict__ W,
                                                       us* __restrict__ Wth, us* __restrict__ Wtl,
                                                       int K, int N){
  __shared__ float tile[32][33];
  int tx = threadIdx.x & 31, ty = threadIdx.x >> 5;   // 32 x 8
  int n0 = blockIdx.x * 32, k0 = blockIdx.y * 32;
  for (int r = 0; r < 32; r += 8)
    tile[ty + r][tx] = W[(size_t)(k0 + ty + r) * N + n0 + tx];
  __syncthreads();
  for (int r = 0; r < 32; r += 8){
    float v = tile[tx][ty + r];
    us h = f2bf(v);
    size_t idx = (size_t)(n0 + ty + r) * K + k0 + tx;
    Wth[idx] = h;
    Wtl[idx] = f2bf(v - bf2f(h));
  }
}

// ---------------- fused projection GEMM (q/k/v or k_data/v_data) ----------------
__global__ __launch_bounds__(256) void gemm_fused(const us* __restrict__ Ah, const us* __restrict__ Al,
                                                  const us* __restrict__ Bth, const us* __restrict__ Btl,
                                                  const float* __restrict__ bias,
                                                  us* __restrict__ Qh, us* __restrict__ Ql,
                                                  us* __restrict__ Kh, us* __restrict__ Kl,
                                                  us* __restrict__ VT,
                                                  int regbase, int kroff){
  __shared__ us sm[16384];  // Ah@0, Bh@4096, Al@8192, Bl@12288
  const int tid = threadIdx.x, wid = tid >> 6, lane = tid & 63;
  const int l15 = lane & 15, l16 = lane >> 4;
  const int row0 = blockIdx.y * 128, col0 = blockIdx.x * 128;
  const int region = (blockIdx.x >> 3) + regbase;
  const bool split = (region < 2);
  const int wr = (wid >> 1) * 64, wc = (wid & 1) * 64;
  f32x4 acc[4][4] = {};

  for (int k0 = 0; k0 < 1024; k0 += 32){
    for (int c = 0; c < 2; ++c){
      int i = c * 256 + tid;                           // 0..511: row=i>>2, k8=(i&3)*8
      size_t aoff = (size_t)(row0 + (i >> 2)) * 1024 + k0 + (i & 3) * 8;
      size_t boff = (size_t)(col0 + (i >> 2)) * 1024 + k0 + (i & 3) * 8;
      GLDS(Ah + aoff, &sm[c * 2048 + wid * 512]);
      GLDS(Bth + boff, &sm[4096 + c * 2048 + wid * 512]);
      if (split){
        GLDS(Al + aoff, &sm[8192 + c * 2048 + wid * 512]);
        GLDS(Btl + boff, &sm[12288 + c * 2048 + wid * 512]);
      }
    }
    __syncthreads();
    bf16x8 afh[4], bfh[4];
    for (int m = 0; m < 4; m++) afh[m] = *(const bf16x8*)&sm[(wr + m * 16 + l15) * 32 + l16 * 8];
    for (int n = 0; n < 4; n++) bfh[n] = *(const bf16x8*)&sm[4096 + (wc + n * 16 + l15) * 32 + l16 * 8];
    if (split){
      bf16x8 afl[4], bfl[4];
      for (int m = 0; m < 4; m++) afl[m] = *(const bf16x8*)&sm[8192 + (wr + m * 16 + l15) * 32 + l16 * 8];
      for (int n = 0; n < 4; n++) bfl[n] = *(const bf16x8*)&sm[12288 + (wc + n * 16 + l15) * 32 + l16 * 8];
      for (int m = 0; m < 4; m++)
        for (int n = 0; n < 4; n++){
          acc[m][n] = __builtin_amdgcn_mfma_f32_16x16x32_bf16(afh[m], bfh[n], acc[m][n], 0, 0, 0);
          acc[m][n] = __builtin_amdgcn_mfma_f32_16x16x32_bf16(afh[m], bfl[n], acc[m][n], 0, 0, 0);
          acc[m][n] = __builtin_amdgcn_mfma_f32_16x16x32_bf16(afl[m], bfh[n], acc[m][n], 0, 0, 0);
        }
    } else {
      for (int m = 0; m < 4; m++)
        for (int n = 0; n < 4; n++)
          acc[m][n] = __builtin_amdgcn_mfma_f32_16x16x32_bf16(afh[m], bfh[n], acc[m][n], 0, 0, 0);
    }
    __syncthreads();
  }

  for (int m = 0; m < 4; m++)
    for (int n = 0; n < 4; n++){
      int gcol = col0 + wc + n * 16 + l15;
      int ocol = gcol & 1023;
      float bv = bias[gcol];
      if (region == 2){                    // V -> VT[b][d][t], vectorized over 4 rows
        int r = row0 + wr + m * 16 + l16 * 4;
        u16x4 o;
        for (int j = 0; j < 4; j++) o[j] = f2bf(acc[m][n][j] + bv);
        *(u16x4*)&VT[((size_t)((r >> 11) * 1024 + ocol)) * 4096 + kroff + (r & 2047)] = o;
      } else {
        us* Ph = (region == 0) ? Qh : Kh;
        us* Pllo = (region == 0) ? Ql : Kl;
        for (int j = 0; j < 4; j++){
          int r = row0 + wr + m * 16 + l16 * 4 + j;
          size_t orow = (region == 0) ? (size_t)r
                                      : (size_t)((r >> 11) * 4096 + kroff + (r & 2047));
          float v = acc[m][n][j] + bv;
          us h = f2bf(v);
          Ph[orow * 1024 + ocol] = h;
          Pllo[orow * 1024 + ocol] = f2bf(v - bf2f(h));
        }
      }
    }
}

// ---------------- output projection GEMM (plain, fp32 out) ----------------
__global__ __launch_bounds__(256) void gemm_proj(const us* __restrict__ Ah,
                                                 const us* __restrict__ Bth,
                                                 const float* __restrict__ bias,
                                                 float* __restrict__ Co){
  __shared__ us sm[8192];
  const int tid = threadIdx.x, wid = tid >> 6, lane = tid & 63;
  const int l15 = lane & 15, l16 = lane >> 4;
  const int row0 = blockIdx.y * 128, col0 = blockIdx.x * 128;
  const int wr = (wid >> 1) * 64, wc = (wid & 1) * 64;
  f32x4 acc[4][4] = {};

  for (int k0 = 0; k0 < 1024; k0 += 32){
    for (int c = 0; c < 2; ++c){
      int i = c * 256 + tid;
      size_t aoff = (size_t)(row0 + (i >> 2)) * 1024 + k0 + (i & 3) * 8;
      size_t boff = (size_t)(col0 + (i >> 2)) * 1024 + k0 + (i & 3) * 8;
      GLDS(Ah + aoff, &sm[c * 2048 + wid * 512]);
      GLDS(Bth + boff, &sm[4096 + c * 2048 + wid * 512]);
    }
    __syncthreads();
    bf16x8 afh[4], bfh[4];
    for (int m = 0; m < 4; m++) afh[m] = *(const bf16x8*)&sm[(wr + m * 16 + l15) * 32 + l16 * 8];
    for (int n = 0; n < 4; n++) bfh[n] = *(const bf16x8*)&sm[4096 + (wc + n * 16 + l15) * 32 + l16 * 8];
    for (int m = 0; m < 4; m++)
      for (int n = 0; n < 4; n++)
        acc[m][n] = __builtin_amdgcn_mfma_f32_16x16x32_bf16(afh[m], bfh[n], acc[m][n], 0, 0, 0);
    __syncthreads();
  }

  for (int m = 0; m < 4; m++)
    for (int n = 0; n < 4; n++){
      int col = col0 + wc + n * 16 + l15;
      float bv = bias[col];
      for (int j = 0; j < 4; j++){
        int r = row0 + wr + m * 16 + l16 * 4 + j;
        Co[(size_t)r * 1024 + col] = acc[m][n][j] + bv;
      }
    }
}

// ---------------- fused attention: 32x32 MFMA, swapped operands, in-register P ----------------
// grid: B*H*(M/128); 4 waves x 32 q-rows. q = lane&31, hb = lane>>5.
// S^T C-layout (m74/m101): reg 4g+j -> t = ts*32 + 8g + 4*hb + j.
// K,V: LDS double-buffered, write-late + 1 barrier/tile (T14). V staged coalesced, shared by 4 waves.
// P: T12 cvt_pk + v_permlane32_swap (no LDS round trip, 0 bank conflicts).
__global__ __launch_bounds__(256) void attn_kernel(const us* __restrict__ Qh, const us* __restrict__ Ql,
                                                   const us* __restrict__ Kh, const us* __restrict__ Kl,
                                                   const us* __restrict__ VT,
                                                   us* __restrict__ attno){
  __shared__ us Kb[2][2][64 * 72];     // [dbuf][hi/lo][64 t][72]
  __shared__ us Vb[2][64 * 72];        // [dbuf][64 d][72]  (V^T tile: row d, col t)
  const int tid = threadIdx.x, wid = tid >> 6, lane = tid & 63;
  const int l31 = lane & 31, hb = lane >> 5, h8 = hb * 8;
  const int qt = blockIdx.x & 15;             // M/128 = 16
  const int bh = blockIdx.x >> 4;
  const int hd = (bh & 15) * 64, b = bh >> 4;
  const int qrow = qt * 128 + wid * 32 + l31;

  // Q fragments (B operand): lane holds Q[qrow][d = kk*16 + h8 + i]
  bf16x8 qfh[4], qfl[4];
  {
    const us* qp = Qh + (size_t)(b * MM + qrow) * 1024 + hd;
    const us* qq = Ql + (size_t)(b * MM + qrow) * 1024 + hd;
#pragma unroll
    for (int kk = 0; kk < 4; kk++){
      qfh[kk] = *(const bf16x8*)(qp + kk * 16 + h8);
      qfl[kk] = *(const bf16x8*)(qq + kk * 16 + h8);
    }
  }

  const int i0 = tid, i1 = 256 + tid;
  const int kt0 = i0 >> 3, kd0 = (i0 & 7) * 8;
  const int kt1 = i1 >> 3, kd1 = (i1 & 7) * 8;

#define GK(t0_, t_, d_) (((size_t)(b * TT + (t0_) + (t_))) * 1024 + hd + (d_))
#define GV(t0_, d_, t_) (((size_t)b * 1024 + hd + (d_)) * 4096 + (t0_) + (t_))

  // prologue: stage K,V tile 0 into buf 0
  uint4 rKh0 = *(const uint4*)(Kh + GK(0, kt0, kd0));
  uint4 rKh1 = *(const uint4*)(Kh + GK(0, kt1, kd1));
  uint4 rKl0 = *(const uint4*)(Kl + GK(0, kt0, kd0));
  uint4 rKl1 = *(const uint4*)(Kl + GK(0, kt1, kd1));
  uint4 rV0  = *(const uint4*)(VT + GV(0, kt0, kd0));
  uint4 rV1  = *(const uint4*)(VT + GV(0, kt1, kd1));
  *(uint4*)&Kb[0][0][kt0 * 72 + kd0] = rKh0;
  *(uint4*)&Kb[0][0][kt1 * 72 + kd1] = rKh1;
  *(uint4*)&Kb[0][1][kt0 * 72 + kd0] = rKl0;
  *(uint4*)&Kb[0][1][kt1 * 72 + kd1] = rKl1;
  *(uint4*)&Vb[0][kt0 * 72 + kd0] = rV0;
  *(uint4*)&Vb[0][kt1 * 72 + kd1] = rV1;
  __syncthreads();

  f32x16 acc0 = {}, acc1 = {};
  float mrow = -1e30f, lrow = 0.f;
  const float cs = 0.125f * 1.44269504088896f;   // to log2 domain

  for (int t0 = 0; t0 < TT; t0 += 64){
    const int cur = (t0 >> 6) & 1;
    const bool pre = (t0 + 64 < TT);
    if (pre){
      rKh0 = *(const uint4*)(Kh + GK(t0 + 64, kt0, kd0));
      rKh1 = *(const uint4*)(Kh + GK(t0 + 64, kt1, kd1));
      rKl0 = *(const uint4*)(Kl + GK(t0 + 64, kt0, kd0));
      rKl1 = *(const uint4*)(Kl + GK(t0 + 64, kt1, kd1));
      rV0  = *(const uint4*)(VT + GV(t0 + 64, kt0, kd0));
      rV1  = *(const uint4*)(VT + GV(t0 + 64, kt1, kd1));
    }

    // S^T = K . Q^T (split): frag ts holds t = ts*32 + tloc, q = l31
    const us* KbH = &Kb[cur][0][0];
    const us* KbL = &Kb[cur][1][0];
    f32x16 sfr0 = {}, sfr1 = {};
    __builtin_amdgcn_s_setprio(1);
#pragma unroll
    for (int kk = 0; kk < 4; kk++){
      bf16x8 a0h = *(const bf16x8*)&KbH[l31 * 72 + kk * 16 + h8];
      bf16x8 a0l = *(const bf16x8*)&KbL[l31 * 72 + kk * 16 + h8];
      bf16x8 a1h = *(const bf16x8*)&KbH[(32 + l31) * 72 + kk * 16 + h8];
      bf16x8 a1l = *(const bf16x8*)&KbL[(32 + l31) * 72 + kk * 16 + h8];
      sfr0 = __builtin_amdgcn_mfma_f32_32x32x16_bf16(a0h, qfh[kk], sfr0, 0, 0, 0);
      sfr0 = __builtin_amdgcn_mfma_f32_32x32x16_bf16(a0l, qfh[kk], sfr0, 0, 0, 0);
      sfr0 = __builtin_amdgcn_mfma_f32_32x32x16_bf16(a0h, qfl[kk], sfr0, 0, 0, 0);
      sfr1 = __builtin_amdgcn_mfma_f32_32x32x16_bf16(a1h, qfh[kk], sfr1, 0, 0, 0);
      sfr1 = __builtin_amdgcn_mfma_f32_32x32x16_bf16(a1l, qfh[kk], sfr1, 0, 0, 0);
      sfr1 = __builtin_amdgcn_mfma_f32_32x32x16_bf16(a1h, qfl[kk], sfr1, 0, 0, 0);
    }
    __builtin_amdgcn_s_setprio(0);

    // online softmax (log2 domain, T13 defer-max, exp2 arg via fma fold)
    float v = -1e30f;
#pragma unroll
    for (int r = 0; r < 16; r++) v = fmaxf(v, fmaxf(sfr0[r], sfr1[r]));
    float vs = v * cs;
    vs = fmaxf(vs, __shfl_xor(vs, 32, 64));
    if (!__all(vs <= mrow + 8.f)){
      float mn = fmaxf(mrow, vs);
      float rs = __builtin_amdgcn_exp2f(mrow - mn);
      mrow = mn;
      lrow *= rs;
#pragma unroll
      for (int r = 0; r < 16; r++){ acc0[r] *= rs; acc1[r] *= rs; }
    }
    const float nm = -mrow;
    float tsum = 0.f;
    unsigned int A0[4][2], A1[4][2];
#pragma unroll
    for (int g = 0; g < 4; g++){
      float e00 = __builtin_amdgcn_exp2f(__builtin_fmaf(sfr0[4*g+0], cs, nm));
      float e01 = __builtin_amdgcn_exp2f(__builtin_fmaf(sfr0[4*g+1], cs, nm));
      float e02 = __builtin_amdgcn_exp2f(__builtin_fmaf(sfr0[4*g+2], cs, nm));
      float e03 = __builtin_amdgcn_exp2f(__builtin_fmaf(sfr0[4*g+3], cs, nm));
      float e10 = __builtin_amdgcn_exp2f(__builtin_fmaf(sfr1[4*g+0], cs, nm));
      float e11 = __builtin_amdgcn_exp2f(__builtin_fmaf(sfr1[4*g+1], cs, nm));
      float e12 = __builtin_amdgcn_exp2f(__builtin_fmaf(sfr1[4*g+2], cs, nm));
      float e13 = __builtin_amdgcn_exp2f(__builtin_fmaf(sfr1[4*g+3], cs, nm));
      tsum += (e00 + e01) + (e02 + e03) + (e10 + e11) + (e12 + e13);
      A0[g][0] = cvt_pk_bf16(e00, e01);
      A0[g][1] = cvt_pk_bf16(e02, e03);
      A1[g][0] = cvt_pk_bf16(e10, e11);
      A1[g][1] = cvt_pk_bf16(e12, e13);
    }
    tsum += __shfl_xor(tsum, 32, 64);
    lrow += tsum;

    // build P fragments in-register: frag kk = {x'0, x'1, y'0, y'1},
    // (x'_i, y'_i) = permlane32_swap(A[2kkl][i], A[2kkl+1][i])
    bf16x8 pf[4];
#pragma unroll
    for (int kkl = 0; kkl < 2; kkl++){
      unsigned int x0 = A0[2*kkl][0], y0 = A0[2*kkl+1][0];
      unsigned int x1 = A0[2*kkl][1], y1 = A0[2*kkl+1][1];
      plane_swap(x0, y0);
      plane_swap(x1, y1);
      u32x4 w = {x0, x1, y0, y1};
      pf[kkl] = __builtin_bit_cast(bf16x8, w);
      unsigned int z0 = A1[2*kkl][0], t0w = A1[2*kkl+1][0];
      unsigned int z1 = A1[2*kkl][1], t1w = A1[2*kkl+1][1];
      plane_swap(z0, t0w);
      plane_swap(z1, t1w);
      u32x4 w2 = {z0, z1, t0w, t1w};
      pf[2 + kkl] = __builtin_bit_cast(bf16x8, w2);
    }

    // O^T += V^T . P^T : A = V^T rows (LDS, shared), B = P (in-register)
    const us* VbC = &Vb[cur][0];
    __builtin_amdgcn_s_setprio(1);
#pragma unroll
    for (int kk = 0; kk < 4; kk++){
      bf16x8 av0 = *(const bf16x8*)&VbC[l31 * 72 + kk * 16 + h8];
      bf16x8 av1 = *(const bf16x8*)&VbC[(32 + l31) * 72 + kk * 16 + h8];
      acc0 = __builtin_amdgcn_mfma_f32_32x32x16_bf16(av0, pf[kk], acc0, 0, 0, 0);
      acc1 = __builtin_amdgcn_mfma_f32_32x32x16_bf16(av1, pf[kk], acc1, 0, 0, 0);
    }
    __builtin_amdgcn_s_setprio(0);

    // stage next tile into the other buffer, then single barrier
    if (pre){
      const int nxt = cur ^ 1;
      *(uint4*)&Kb[nxt][0][kt0 * 72 + kd0] = rKh0;
      *(uint4*)&Kb[nxt][0][kt1 * 72 + kd1] = rKh1;
      *(uint4*)&Kb[nxt][1][kt0 * 72 + kd0] = rKl0;
      *(uint4*)&Kb[nxt][1][kt1 * 72 + kd1] = rKl1;
      *(uint4*)&Vb[nxt][kt0 * 72 + kd0] = rV0;
      *(uint4*)&Vb[nxt][kt1 * 72 + kd1] = rV1;
    }
    __syncthreads();
  }
#undef GK
#undef GV

  float inv = 1.f / lrow;
  us* op = attno + (size_t)(b * MM + qrow) * 1024 + hd;
#pragma unroll
  for (int g = 0; g < 4; g++){
    bf16x4 w0, w1;
#pragma unroll
    for (int j = 0; j < 4; j++){
      w0[j] = (__bf16)(acc0[4 * g + j] * inv);
      w1[j] = (__bf16)(acc1[4 * g + j] * inv);
    }
    *(u16x4*)&op[8 * g + 4 * hb]      = __builtin_bit_cast(u16x4, w0);
    *(u16x4*)&op[32 + 8 * g + 4 * hb] = __builtin_bit_cast(u16x4, w1);
  }
}

extern "C" void kernel_launch(void* const* d_in, const int* in_sizes, int n_in,
                              void* d_out, int out_size, void* d_ws, size_t ws_size,
                              hipStream_t stream){
  const float* x      = (const float*)d_in[0];
  const float* data   = (const float*)d_in[1];
  const float* W_attn = (const float*)d_in[2];
  const float* b_attn = (const float*)d_in[3];
  const float* W_data = (const float*)d_in[4];
  const float* b_data = (const float*)d_in[5];
  const float* W_proj = (const float*)d_in[6];
  const float* b_proj = (const float*)d_in[7];
  float* out = (float*)d_out;

  char* ws = (char*)d_ws;
  us* xb_hi  = (us*)(ws + 0);            // 4096x1024 (8 MB each)
  us* xb_lo  = (us*)(ws + 8388608);
  us* db_hi  = (us*)(ws + 16777216);
  us* db_lo  = (us*)(ws + 25165824);
  us* Wat_hi = (us*)(ws + 33554432);     // 3072x1024 (6 MB each)
  us* Wat_lo = (us*)(ws + 39845888);
  us* Wdt_hi = (us*)(ws + 46137344);     // 2048x1024 (4 MB each)
  us* Wdt_lo = (us*)(ws + 50331648);
  us* Wpt_hi = (us*)(ws + 54525952);     // 1024x1024 (2 MB each)
  us* Wpt_lo = (us*)(ws + 56623104);
  us* Qh     = (us*)(ws + 58720256);     // [2][2048][1024] (8 MB each)
  us* Ql     = (us*)(ws + 67108864);
  us* Kh     = (us*)(ws + 75497472);     // [2][4096][1024] (16 MB each)
  us* Kl     = (us*)(ws + 92274688);
  us* VT     = (us*)(ws + 109051904);    // [2][1024][4096] transposed V (16 MB)
  us* attno  = (us*)(ws + 16777216);     // alias db_hi (db consumed before attn runs)

  split_cast<<<2048, 256, 0, stream>>>(x, xb_hi, xb_lo);
  split_cast<<<2048, 256, 0, stream>>>(data, db_hi, db_lo);
  transpose_split<<<dim3(96, 32), 256, 0, stream>>>(W_attn, Wat_hi, Wat_lo, 1024, 3072);
  transpose_split<<<dim3(64, 32), 256, 0, stream>>>(W_data, Wdt_hi, Wdt_lo, 1024, 2048);
  transpose_split<<<dim3(32, 32), 256, 0, stream>>>(W_proj, Wpt_hi, Wpt_lo, 1024, 1024);

  // q,k,v = x @ W_attn (+b): regions 0,1,2 -> Qh/Ql, Kh/Kl@roff0, VT@roff0
  gemm_fused<<<dim3(24, 32), 256, 0, stream>>>(xb_hi, xb_lo, Wat_hi, Wat_lo, b_attn,
                                               Qh, Ql, Kh, Kl, VT, 0, 0);
  // k_data,v_data = data @ W_data (+b): regions 1,2 -> Kh/Kl@roff2048, VT@roff2048
  gemm_fused<<<dim3(16, 32), 256, 0, stream>>>(db_hi, db_lo, Wdt_hi, Wdt_lo, b_data,
                                               nullptr, nullptr, Kh, Kl, VT, 1, 2048);

  attn_kernel<<<512, 256, 0, stream>>>(Qh, Ql, Kh, Kl, VT, attno);

  gemm_proj<<<dim3(8, 32), 256, 0, stream>>>(attno, Wpt_hi, b_proj, out);
}